// Round 7
// baseline (122.873 us; speedup 1.0000x reference)
//
#include <hip/hip_runtime.h>
#include <math.h>

#define B_ 2
#define T_ 16
#define N_ 128
#define CI 64
#define CO 128

// ws layout (floats):
//   AQ @ 0       : 524288   AQ[b][oq32][t16][n128][4]  (a + bias)
//   BQ @ 524288  : 524288   BQ[b][oq32][t16][j128][4]  (bpart)
//   CQ @ 1048576 : 4194304  CQ[b][oq32][i128][j128][4] (cpart)
//   WF @ 5242880 : 8192     Wc MFMA B-frags bf16 (term2 x kh2 x ot8 x lane64 x u8)
#define AQ_OFF 0
#define BQ_OFF 524288
#define CQ_OFF 1048576
#define WF_OFF 5242880

typedef __attribute__((ext_vector_type(8))) short short8;
typedef __attribute__((ext_vector_type(4))) float f32x4;

__device__ __forceinline__ float4 f4add(float4 a, float4 b) {
  return make_float4(a.x + b.x, a.y + b.y, a.z + b.z, a.w + b.w);
}
__device__ __forceinline__ float4 f4max(float4 a, float4 b) {
  return make_float4(fmaxf(a.x, b.x), fmaxf(a.y, b.y), fmaxf(a.z, b.z), fmaxf(a.w, b.w));
}
__device__ __forceinline__ float4 f4min(float4 a, float4 b) {
  return make_float4(fminf(a.x, b.x), fminf(a.y, b.y), fminf(a.z, b.z), fminf(a.w, b.w));
}
__device__ __forceinline__ void f4fma(float4& acc, float s, float4 v) {
  acc.x = fmaf(s, v.x, acc.x);
  acc.y = fmaf(s, v.y, acc.y);
  acc.z = fmaf(s, v.z, acc.z);
  acc.w = fmaf(s, v.w, acc.w);
}
__device__ __forceinline__ float silu1(float v) { return v / (1.0f + __expf(-v)); }
__device__ __forceinline__ float4 silu4(float4 v) {
  return make_float4(silu1(v.x), silu1(v.y), silu1(v.z), silu1(v.w));
}
__device__ __forceinline__ unsigned int bf2(float a, float b) {
  unsigned int ua = __float_as_uint(a);
  unsigned int ub = __float_as_uint(b);
  ua = (ua + 0x7FFFu + ((ua >> 16) & 1u)) >> 16;
  ub = (ub + 0x7FFFu + ((ub >> 16) & 1u)) >> 16;
  return (ub << 16) | ua;
}
__device__ __forceinline__ uint4 pack8(float4 lo, float4 hi) {
  return make_uint4(bf2(lo.x, lo.y), bf2(lo.z, lo.w), bf2(hi.x, hi.y), bf2(hi.z, hi.w));
}

// =====================================================================
// k_prepW: pack Wc1/Wc2 into MFMA B-frag order (bf16). grid 8 x 256.
// B-frag (16x16x32): lane holds B[k=(lane>>4)*8+u][n=lane&15].
// =====================================================================
__global__ __launch_bounds__(256) void k_prepW(const float* __restrict__ W,
                                               float* __restrict__ WF) {
  int fid = blockIdx.x * 256 + threadIdx.x;     // 0..2047
  int lane = fid & 63;
  int ot   = (fid >> 6) & 7;
  int kh   = (fid >> 9) & 1;
  int term = fid >> 10;
  int o  = ot * 16 + (lane & 15);
  int kb = kh * 32 + (lane >> 4) * 8;
  float v[8];
  #pragma unroll
  for (int u = 0; u < 8; u++)
    v[u] = W[(384 + term * 64 + kb + u) * 128 + o];
  ((uint4*)WF)[fid] = pack8(make_float4(v[0], v[1], v[2], v[3]),
                            make_float4(v[4], v[5], v[6], v[7]));
}

// =====================================================================
// k_ab2 (unchanged, known-good): A/Bp from x and W directly.
// grid 512 = b(2) x t(16) x dst(2) x nq(8); 256 thr.
// =====================================================================
__global__ __launch_bounds__(256) void k_ab2(
    const float* __restrict__ x, const float* __restrict__ W,
    const float* __restrict__ bias, float* __restrict__ AQ, float* __restrict__ BQ)
{
  __shared__ __align__(16) float WL[64 * 128];  // [c][o]
  __shared__ float xT[64 * 17];                 // [c][n], stride 17

  int blk = blockIdx.x;
  int nq  = blk & 7;
  int dst = (blk >> 3) & 1;
  int t   = (blk >> 4) & 15;
  int b   = blk >> 8;
  float f0 = (t != 0)      ? 1.0f : 0.0f;
  float f2 = (t != T_ - 1) ? 1.0f : 0.0f;
  int tid = threadIdx.x;

  const float4* W4 = (const float4*)W;
  float4* WL4 = (float4*)WL;
  int wb = dst * 6144;
  #pragma unroll
  for (int k = 0; k < 8; k++) {
    int idx4 = tid + k * 256;
    float4 wa = W4[wb + idx4];
    float4 wm = W4[wb + 2048 + idx4];
    float4 wc = W4[wb + 4096 + idx4];
    WL4[idx4] = make_float4(f0 * wa.x + wm.x + f2 * wc.x,
                            f0 * wa.y + wm.y + f2 * wc.y,
                            f0 * wa.z + wm.z + f2 * wc.z,
                            f0 * wa.w + wm.w + f2 * wc.w);
  }
  {
    long xb = ((long)(b * T_ + t) * N_ + nq * 16) * CI;
    #pragma unroll
    for (int k = 0; k < 4; k++) {
      int idx = tid + k * 256;
      int c = idx & 63, n = idx >> 6;
      xT[c * 17 + n] = x[xb + n * CI + c];
    }
  }
  __syncthreads();

  int nl = tid & 15;
  int qg = tid >> 4;
  float4 acc0, acc1;
  if (dst == 0) {
    acc0 = ((const float4*)bias)[qg * 2];
    acc1 = ((const float4*)bias)[qg * 2 + 1];
  } else {
    acc0 = make_float4(0, 0, 0, 0); acc1 = acc0;
  }
  #pragma unroll 8
  for (int c = 0; c < 64; c++) {
    float xv = xT[c * 17 + nl];
    float4 w0 = WL4[c * 32 + qg * 2];
    float4 w1 = WL4[c * 32 + qg * 2 + 1];
    f4fma(acc0, xv, w0);
    f4fma(acc1, xv, w1);
  }
  float* dp = dst ? BQ : AQ;
  int n = nq * 16 + nl;
  long u0 = ((long)(b * 32 + qg * 2) * 16 + t) * 128 + n;
  long u1 = u0 + 16 * 128;
  ((float4*)dp)[u0] = acc0;
  ((float4*)dp)[u1] = acc1;
}

// =====================================================================
// k_cp4: Cp via bf16 MFMA, j-half split. grid 512 = (b, i, jh); 256 thr.
// Wave w owns j-tile w (local), 8 o-tiles, K=64 x 2 terms = 32 MFMA/wave.
// LDS 48 KB (AF 16K + WcF 32K; Cp[64][132] f32 overlays) -> 3 blocks/CU.
// Store: consecutive lanes -> consecutive j (1 KB contiguous / instr).
// =====================================================================
__global__ __launch_bounds__(256) void k_cp4(
    const float* __restrict__ cond, const float* __restrict__ WF,
    float* __restrict__ CQ)
{
  __shared__ __align__(16) unsigned char smem[49152];
  uint4* AF  = (uint4*)smem;             // 1024 frags: [term2][jtl4 x kh2][lane64]
  uint4* WcF = (uint4*)(smem + 16384);   // 2048 frags: [term][kh][ot][lane]
  float* Cp  = (float*)smem;             // overlay: [j 64][o 128] stride 132

  int blk = blockIdx.x;
  int jh = blk & 1;
  int i  = (blk >> 1) & 127;
  int b  = blk >> 8;
  int tid = threadIdx.x;

  // stage Wc fragments (32 KB coalesced copy)
  {
    const uint4* src = (const uint4*)WF;
    #pragma unroll
    for (int k = 0; k < 8; k++) WcF[tid + k * 256] = src[tid + k * 256];
  }
  // stage A fragments (both terms, this j-half)
  #pragma unroll
  for (int k = 0; k < 4; k++) {
    int idx = tid + k * 256;                    // [term2][jl64][oct8]
    int term = idx >> 9;
    int rem = idx & 511;
    int jl = rem >> 3, oct = rem & 7;
    long row = (term == 0) ? ((long)(b * N_ + i) * N_ + jh * 64 + jl)
                           : ((long)(b * N_ + jh * 64 + jl) * N_ + i);
    const float4* src = (const float4*)(cond + row * 64 + oct * 8);
    float4 lo = src[0], hi = src[1];
    int frag = term * 512 + ((jl >> 4) * 2 + (oct >> 2)) * 64 + (oct & 3) * 16 + (jl & 15);
    AF[frag] = pack8(lo, hi);
  }
  __syncthreads();

  int lane = tid & 63;
  int w    = tid >> 6;
  f32x4 acc[8];
  #pragma unroll
  for (int ot = 0; ot < 8; ot++) {
    acc[ot][0] = 0.f; acc[ot][1] = 0.f; acc[ot][2] = 0.f; acc[ot][3] = 0.f;
  }
  const short8* AF8 = (const short8*)AF;
  const short8* WF8 = (const short8*)WcF;
  #pragma unroll
  for (int term = 0; term < 2; term++) {
    #pragma unroll
    for (int kh = 0; kh < 2; kh++) {
      short8 a = AF8[term * 512 + (w * 2 + kh) * 64 + lane];
      #pragma unroll
      for (int ot = 0; ot < 8; ot++) {
        short8 bv = WF8[((term * 2 + kh) * 8 + ot) * 64 + lane];
        acc[ot] = __builtin_amdgcn_mfma_f32_16x16x32_bf16(a, bv, acc[ot], 0, 0, 0);
      }
    }
  }
  __syncthreads();   // frag reads done; overlay Cp

  // epilogue: acc -> Cp[j_local][o], row stride 132
  {
    int col = lane & 15;
    int row0 = w * 16 + (lane >> 4) * 4;
    #pragma unroll
    for (int ot = 0; ot < 8; ot++) {
      f32x4 d = acc[ot];
      int cbase = ot * 16 + col;
      Cp[(row0 + 0) * 132 + cbase] = d[0];
      Cp[(row0 + 1) * 132 + cbase] = d[1];
      Cp[(row0 + 2) * 132 + cbase] = d[2];
      Cp[(row0 + 3) * 132 + cbase] = d[3];
    }
  }
  __syncthreads();

  // store CQ[b][oq][i][j]: lanes = 64 consecutive j -> contiguous 1 KB
  {
    const float4* Cp4 = (const float4*)Cp;      // unit = j*33 + oq
    float4* CQ4 = (float4*)CQ;
    #pragma unroll
    for (int it = 0; it < 8; it++) {
      int idx = tid + it * 256;                 // 2048 = oq(32) x jl(64)
      int oq = idx >> 6, jl = idx & 63;
      CQ4[((long)(b * 32 + oq) * 128 + i) * 128 + jh * 64 + jl] = Cp4[jl * 33 + oq];
    }
  }
}

// =====================================================================
// k_red6: out[b,t,i,o] = max(silu(A+mx), silu(A+mn)), mx/mn = max/min_j(Bp+Cp)
// grid 512 = b(2) x oq(32) x th(2) x iq(4); 256 thr.
// lane = (t 8, i 8): t-lanes share CQ lines, i-lanes share BQ lines ->
// every load-instr is 8 line-resident segments. Thread owns one (t,i,oq)
// over all j: NO LDS, NO barrier, NO shfl. One float4 out per thread.
// =====================================================================
__global__ __launch_bounds__(256) void k_red6(
    const float* __restrict__ AQ, const float* __restrict__ BQ,
    const float* __restrict__ CQ, float* __restrict__ out)
{
  int blk = blockIdx.x;
  int iq = blk & 3;
  int th = (blk >> 2) & 1;
  int oq = (blk >> 3) & 31;
  int b  = blk >> 8;
  int tid = threadIdx.x;
  int w    = tid >> 6;
  int lane = tid & 63;
  int t = th * 8 + (lane >> 3);
  int i = iq * 32 + w * 8 + (lane & 7);

  const float4* CQr = (const float4*)CQ + ((long)(b * 32 + oq) * 128 + i) * 128;
  const float4* BQr = (const float4*)BQ + ((long)(b * 32 + oq) * 16 + t) * 128;

  float4 mx0 = make_float4(-3.4e38f, -3.4e38f, -3.4e38f, -3.4e38f);
  float4 mx1 = mx0;
  float4 mn0 = make_float4(3.4e38f, 3.4e38f, 3.4e38f, 3.4e38f);
  float4 mn1 = mn0;

  #pragma unroll 4
  for (int j = 0; j < 128; j += 2) {
    float4 s0 = f4add(CQr[j],     BQr[j]);
    float4 s1 = f4add(CQr[j + 1], BQr[j + 1]);
    mx0 = f4max(mx0, s0); mn0 = f4min(mn0, s0);
    mx1 = f4max(mx1, s1); mn1 = f4min(mn1, s1);
  }
  float4 mx = f4max(mx0, mx1);
  float4 mn = f4min(mn0, mn1);

  float4 av = ((const float4*)AQ)[((long)(b * 32 + oq) * 16 + t) * 128 + i];
  float4 M  = f4add(mx, av);
  float4 Mn = f4add(mn, av);
  float4 res = f4max(silu4(M), silu4(Mn));
  ((float4*)out)[(long)((b * 16 + t) * 128 + i) * 32 + oq] = res;
}

extern "C" void kernel_launch(void* const* d_in, const int* in_sizes, int n_in,
                              void* d_out, int out_size, void* d_ws, size_t ws_size,
                              hipStream_t stream) {
  const float* x    = (const float*)d_in[0];   // (2,16,128,64)
  const float* cond = (const float*)d_in[1];   // (2,128,128,64)
  const float* W    = (const float*)d_in[2];   // (512,128)
  const float* bias = (const float*)d_in[3];   // (128,)
  float* out = (float*)d_out;                  // (2,16,128,128)

  float* ws = (float*)d_ws;
  float* AQ = ws + AQ_OFF;
  float* BQ = ws + BQ_OFF;
  float* CQ = ws + CQ_OFF;
  float* WF = ws + WF_OFF;

  k_prepW<<<8, 256, 0, stream>>>(W, WF);
  k_ab2<<<512, 256, 0, stream>>>(x, W, bias, AQ, BQ);
  k_cp4<<<512, 256, 0, stream>>>(cond, WF, CQ);
  k_red6<<<512, 256, 0, stream>>>(AQ, BQ, CQ, out);
}

// Round 8
// 93.450 us; speedup vs baseline: 1.3149x; 1.3149x over previous
//
#include <hip/hip_runtime.h>
#include <math.h>

#define B_ 2
#define T_ 16
#define N_ 128
#define CI 64
#define CO 128

// ws layout (floats):
//   AQ @ 0       : 524288   AQ[b][oq32][t16][i128][4]  (a + bias)
//   BT @ 524288  : 524288   BT[b][t16][j128][oq32][4]  (bpart, reducer-friendly)
#define AQ_OFF 0
#define BT_OFF 524288

typedef __attribute__((ext_vector_type(8))) short short8;
typedef __attribute__((ext_vector_type(4))) float f32x4;

__device__ __forceinline__ float4 f4add(float4 a, float4 b) {
  return make_float4(a.x + b.x, a.y + b.y, a.z + b.z, a.w + b.w);
}
__device__ __forceinline__ float4 f4max(float4 a, float4 b) {
  return make_float4(fmaxf(a.x, b.x), fmaxf(a.y, b.y), fmaxf(a.z, b.z), fmaxf(a.w, b.w));
}
__device__ __forceinline__ float4 f4min(float4 a, float4 b) {
  return make_float4(fminf(a.x, b.x), fminf(a.y, b.y), fminf(a.z, b.z), fminf(a.w, b.w));
}
__device__ __forceinline__ void f4fma(float4& acc, float s, float4 v) {
  acc.x = fmaf(s, v.x, acc.x);
  acc.y = fmaf(s, v.y, acc.y);
  acc.z = fmaf(s, v.z, acc.z);
  acc.w = fmaf(s, v.w, acc.w);
}
__device__ __forceinline__ float silu1(float v) { return v / (1.0f + __expf(-v)); }
__device__ __forceinline__ float4 silu4(float4 v) {
  return make_float4(silu1(v.x), silu1(v.y), silu1(v.z), silu1(v.w));
}
__device__ __forceinline__ float4 shfl4x(float4 v, int m) {
  return make_float4(__shfl_xor(v.x, m, 64), __shfl_xor(v.y, m, 64),
                     __shfl_xor(v.z, m, 64), __shfl_xor(v.w, m, 64));
}
__device__ __forceinline__ unsigned int bf2(float a, float b) {
  unsigned int ua = __float_as_uint(a);
  unsigned int ub = __float_as_uint(b);
  ua = (ua + 0x7FFFu + ((ua >> 16) & 1u)) >> 16;
  ub = (ub + 0x7FFFu + ((ub >> 16) & 1u)) >> 16;
  return (ub << 16) | ua;
}
__device__ __forceinline__ uint4 pack8(float4 lo, float4 hi) {
  return make_uint4(bf2(lo.x, lo.y), bf2(lo.z, lo.w), bf2(hi.x, hi.y), bf2(hi.z, hi.w));
}

// =====================================================================
// k_ab3: A/Bp GEMM (k_ab2 structure). grid 512 = b(2) x t(16) x dst(2) x nq(8);
// 256 thr. dst0 -> AQ[b][oq][t][i] (unchanged); dst1 -> BT[b][t][j][oq] (NEW:
// reducer lane=(jh,oq) gets 512B-contiguous segments).
// =====================================================================
__global__ __launch_bounds__(256) void k_ab3(
    const float* __restrict__ x, const float* __restrict__ W,
    const float* __restrict__ bias, float* __restrict__ AQ, float* __restrict__ BT)
{
  __shared__ __align__(16) float WL[64 * 128];  // [c][o]
  __shared__ float xT[64 * 17];                 // [c][n], stride 17

  int blk = blockIdx.x;
  int nq  = blk & 7;
  int dst = (blk >> 3) & 1;
  int t   = (blk >> 4) & 15;
  int b   = blk >> 8;
  float f0 = (t != 0)      ? 1.0f : 0.0f;
  float f2 = (t != T_ - 1) ? 1.0f : 0.0f;
  int tid = threadIdx.x;

  const float4* W4 = (const float4*)W;
  float4* WL4 = (float4*)WL;
  int wb = dst * 6144;                          // dst0: W rows 0..192; dst1: 192..384
  #pragma unroll
  for (int k = 0; k < 8; k++) {
    int idx4 = tid + k * 256;
    float4 wa = W4[wb + idx4];
    float4 wm = W4[wb + 2048 + idx4];
    float4 wc = W4[wb + 4096 + idx4];
    WL4[idx4] = make_float4(f0 * wa.x + wm.x + f2 * wc.x,
                            f0 * wa.y + wm.y + f2 * wc.y,
                            f0 * wa.z + wm.z + f2 * wc.z,
                            f0 * wa.w + wm.w + f2 * wc.w);
  }
  {
    long xb = ((long)(b * T_ + t) * N_ + nq * 16) * CI;
    #pragma unroll
    for (int k = 0; k < 4; k++) {
      int idx = tid + k * 256;
      int c = idx & 63, n = idx >> 6;
      xT[c * 17 + n] = x[xb + n * CI + c];
    }
  }
  __syncthreads();

  int nl = tid & 15;
  int qg = tid >> 4;                            // quads 2qg, 2qg+1
  float4 acc0, acc1;
  if (dst == 0) {
    acc0 = ((const float4*)bias)[qg * 2];
    acc1 = ((const float4*)bias)[qg * 2 + 1];
  } else {
    acc0 = make_float4(0, 0, 0, 0); acc1 = acc0;
  }
  #pragma unroll 8
  for (int c = 0; c < 64; c++) {
    float xv = xT[c * 17 + nl];
    float4 w0 = WL4[c * 32 + qg * 2];
    float4 w1 = WL4[c * 32 + qg * 2 + 1];
    f4fma(acc0, xv, w0);
    f4fma(acc1, xv, w1);
  }
  int n = nq * 16 + nl;
  if (dst == 0) {
    long u0 = ((long)(b * 32 + qg * 2) * 16 + t) * 128 + n;
    ((float4*)AQ)[u0]            = acc0;
    ((float4*)AQ)[u0 + 16 * 128] = acc1;
  } else {
    long u0 = (((long)(b * 16 + t) * 128) + n) * 32 + qg * 2;
    ((float4*)BT)[u0]     = acc0;
    ((float4*)BT)[u0 + 1] = acc1;
  }
}

// =====================================================================
// k_fused: per (b,i) block (256 blocks, 256 thr = 4 waves):
//  Phase A: build Wc B-frags in LDS (from W directly), stage cond A-frags,
//   bf16 MFMA -> Cp[j 128][o 128] f32 overlay (64 KB LDS union, cp3-verified).
//  Phase B: lane=(jh2, oq32); wave w owns t in {4w..4w+3}. Stream BT[b][t]
//   (L2-resident, 512B-coalesced), 8-deep load batches, in-lane max/min over
//   64 j's, shfl_xor(32) jh-combine, out = max(silu(A+mx), silu(A+mn)).
//  No CQ workspace round-trip; 2 barriers total.
// =====================================================================
__global__ __launch_bounds__(256) void k_fused(
    const float* __restrict__ cond, const float* __restrict__ W,
    const float* __restrict__ AQ, const float* __restrict__ BT,
    float* __restrict__ out)
{
  __shared__ __align__(16) unsigned char smem[65536];
  uint4* AF  = (uint4*)smem;             // 2048 frags: [term][jt8 x kh2][lane64]
  uint4* WcF = (uint4*)(smem + 32768);   // 2048 frags: [term][kh][ot][lane]
  float* Cp  = (float*)smem;             // overlay: [j][o] stride 128

  int blk = blockIdx.x;
  int i = blk & 127;
  int b = blk >> 7;
  int tid = threadIdx.x;

  // ---- build Wc fragments in-block (8 frags/thread) ----
  #pragma unroll
  for (int f = 0; f < 8; f++) {
    int fid = tid + f * 256;                    // [term2][kh2][ot8][lane64]
    int lane_f = fid & 63;
    int ot   = (fid >> 6) & 7;
    int kh   = (fid >> 9) & 1;
    int term = fid >> 10;
    int o  = ot * 16 + (lane_f & 15);
    int kb = kh * 32 + (lane_f >> 4) * 8;
    float v[8];
    #pragma unroll
    for (int u = 0; u < 8; u++)
      v[u] = W[(384 + term * 64 + kb + u) * 128 + o];
    WcF[fid] = pack8(make_float4(v[0], v[1], v[2], v[3]),
                     make_float4(v[4], v[5], v[6], v[7]));
  }
  // ---- stage cond A-fragments (both terms) ----
  #pragma unroll
  for (int term = 0; term < 2; term++) {
    #pragma unroll
    for (int k2 = 0; k2 < 4; k2++) {
      int idx = tid + k2 * 256;                 // j(128) x oct(8)
      int j = idx >> 3, oct = idx & 7;
      long row = (term == 0) ? ((long)(b * N_ + i) * N_ + j)
                             : ((long)(b * N_ + j) * N_ + i);
      const float4* src = (const float4*)(cond + row * 64 + oct * 8);
      float4 lo = src[0], hi = src[1];
      int frag = ((j >> 4) * 2 + (oct >> 2)) * 64 + ((oct & 3) * 16 + (j & 15));
      AF[term * 1024 + frag] = pack8(lo, hi);
    }
  }
  __syncthreads();

  // ---- MFMA: Cp = cond[b,i,:,:]@Wc1 + cond[b,:,i,:]@Wc2 ----
  int lane = tid & 63;
  int w    = tid >> 6;
  f32x4 acc[2][8];
  #pragma unroll
  for (int jt = 0; jt < 2; jt++)
    #pragma unroll
    for (int ot = 0; ot < 8; ot++) {
      acc[jt][ot][0] = 0.f; acc[jt][ot][1] = 0.f;
      acc[jt][ot][2] = 0.f; acc[jt][ot][3] = 0.f;
    }
  const short8* AF8 = (const short8*)AF;
  const short8* WF8 = (const short8*)WcF;
  #pragma unroll
  for (int term = 0; term < 2; term++) {
    #pragma unroll
    for (int kh = 0; kh < 2; kh++) {
      short8 a0 = AF8[term * 1024 + ((2 * w + 0) * 2 + kh) * 64 + lane];
      short8 a1 = AF8[term * 1024 + ((2 * w + 1) * 2 + kh) * 64 + lane];
      #pragma unroll
      for (int ot = 0; ot < 8; ot++) {
        short8 bv = WF8[((term * 2 + kh) * 8 + ot) * 64 + lane];
        acc[0][ot] = __builtin_amdgcn_mfma_f32_16x16x32_bf16(a0, bv, acc[0][ot], 0, 0, 0);
        acc[1][ot] = __builtin_amdgcn_mfma_f32_16x16x32_bf16(a1, bv, acc[1][ot], 0, 0, 0);
      }
    }
  }
  __syncthreads();   // frag reads done; overlay Cp

  // ---- epilogue: acc -> Cp[j][o] stride 128 (C layout: col=lane&15, row=quad*4+reg) ----
  {
    int col = lane & 15;
    int rsub = (lane >> 4) * 4;
    #pragma unroll
    for (int jt = 0; jt < 2; jt++) {
      int row0 = (2 * w + jt) * 16 + rsub;
      #pragma unroll
      for (int ot = 0; ot < 8; ot++) {
        f32x4 d = acc[jt][ot];
        int cbase = ot * 16 + col;
        Cp[(row0 + 0) * 128 + cbase] = d[0];
        Cp[(row0 + 1) * 128 + cbase] = d[1];
        Cp[(row0 + 2) * 128 + cbase] = d[2];
        Cp[(row0 + 3) * 128 + cbase] = d[3];
      }
    }
  }
  __syncthreads();

  // ---- Phase B: streaming max/min reduction over j ----
  int jh = lane >> 5;
  int oq = lane & 31;
  const float4* Cp4 = (const float4*)Cp;        // unit j*32 + oq
  const float4* AQ4 = (const float4*)AQ;
  const float4* BT4 = (const float4*)BT;

  #pragma unroll
  for (int tt = 0; tt < 4; tt++) {
    int t = w * 4 + tt;
    const float4* bq = BT4 + ((long)(b * 16 + t) * 128) * 32;
    float4 mx = make_float4(-3.4e38f, -3.4e38f, -3.4e38f, -3.4e38f);
    float4 mn = make_float4(3.4e38f, 3.4e38f, 3.4e38f, 3.4e38f);
    #pragma unroll
    for (int jj = 0; jj < 64; jj += 8) {
      float4 s[8];
      #pragma unroll
      for (int k = 0; k < 8; k++)
        s[k] = bq[(jh * 64 + jj + k) * 32 + oq];          // 8 loads in flight
      #pragma unroll
      for (int k = 0; k < 8; k++) {
        float4 v = f4add(s[k], Cp4[(jh * 64 + jj + k) * 32 + oq]);
        mx = f4max(mx, v);
        mn = f4min(mn, v);
      }
    }
    mx = f4max(mx, shfl4x(mx, 32));
    mn = f4min(mn, shfl4x(mn, 32));
    if (jh == 0) {
      float4 av = AQ4[((long)(b * 32 + oq) * 16 + t) * 128 + i];
      float4 M  = f4add(mx, av);
      float4 Mn = f4add(mn, av);
      float4 res = f4max(silu4(M), silu4(Mn));
      ((float4*)out)[(long)((b * 16 + t) * 128 + i) * 32 + oq] = res;
    }
  }
}

extern "C" void kernel_launch(void* const* d_in, const int* in_sizes, int n_in,
                              void* d_out, int out_size, void* d_ws, size_t ws_size,
                              hipStream_t stream) {
  const float* x    = (const float*)d_in[0];   // (2,16,128,64)
  const float* cond = (const float*)d_in[1];   // (2,128,128,64)
  const float* W    = (const float*)d_in[2];   // (512,128)
  const float* bias = (const float*)d_in[3];   // (128,)
  float* out = (float*)d_out;                  // (2,16,128,128)

  float* ws = (float*)d_ws;
  float* AQ = ws + AQ_OFF;
  float* BT = ws + BT_OFF;

  k_ab3<<<512, 256, 0, stream>>>(x, W, bias, AQ, BT);
  k_fused<<<256, 256, 0, stream>>>(cond, W, AQ, BT, out);
}